// Round 10
// baseline (329.261 us; speedup 1.0000x reference)
//
#include <hip/hip_runtime.h>
#include <hip/hip_bf16.h>

#define B_ 8
#define S_ 128
#define H_ 512
#define E_ 512
#define NST 8
#define R_ 1024
#define N2 2048
#define KD 512
#define LDA 72          // LDS row pitch in shorts (fragment ds_read_b128: 2-way = free)
#define NBLK 512        // chain grid: 2 blocks/CU x 256 CUs, co-resident by construction
#define GRP 64          // blocks per barrier group (8 groups)

typedef __hip_bfloat16 bf16;
typedef __attribute__((ext_vector_type(8))) short v8s;
typedef __attribute__((ext_vector_type(4))) float v4f;
typedef unsigned long long u64;

__device__ __forceinline__ float sigm(float x){ return 1.0f/(1.0f + expf(-x)); }
__device__ __forceinline__ float load_in(const void* p, long long i, int isb){
    return isb ? __bfloat162float(((const bf16*)p)[i]) : ((const float*)p)[i];
}
__device__ __forceinline__ int idx_read(const int* p, int j, int is64){
    return is64 ? p[2*j] : p[j];
}
__device__ __forceinline__ unsigned short f2b(float v){
    bf16 b = __float2bfloat16(v);
    return *(unsigned short*)&b;
}

// ---- MALL (agent-scope) STORES for cross-phase tensors: bypass L2 -> nothing
// dirty -> no wbl2 needed at barriers. READS are normal cached loads; coherence
// comes from barrier-time invalidation (1 L2-inv per XCD + per-block L1-inv),
// replicating the HSA kernel-dispatch acquire at 1/64 of r3's per-block cost.
__device__ __forceinline__ void vstore1(float* p, float v){
    __hip_atomic_store(p, v, __ATOMIC_RELAXED, __HIP_MEMORY_SCOPE_AGENT);
}
__device__ __forceinline__ void vstore_hb2(unsigned short* p, unsigned short a, unsigned short b){
    unsigned int u = (unsigned)a | ((unsigned)b << 16);
    __hip_atomic_store((unsigned int*)p, u, __ATOMIC_RELAXED, __HIP_MEMORY_SCOPE_AGENT);
}

__device__ __forceinline__ int get_xcd(){
    int x;
    asm volatile("s_getreg_b32 %0, hwreg(HW_REG_XCC_ID)" : "=s"(x));
    return x & 7;
}

// Two-level counter-only grid barrier (proven r4/r7) + optional cache-invalidate.
// bar layout (64-int stride): [0] global ctr; [1+g] group arrive; [9+g] group done;
// [17+x] xcnt (blocks on XCD x); [25+x] inv arrive; [33+x] inv release.
// inv_gen>0: after global release, per-XCD leader does buffer_inv sc0 sc1 (L1+L2),
// others wait then buffer_inv sc0 (own CU L1 only - parallel, cheap).
__device__ __forceinline__ void gsync(int* bar, int gen, int inv_gen){
    __syncthreads();
    if (threadIdx.x == 0){
        int g = blockIdx.x >> 6;
        int* ga = bar + 64*(1+g);
        int* gd = bar + 64*(9+g);
        int old = __hip_atomic_fetch_add(ga, 1, __ATOMIC_RELAXED, __HIP_MEMORY_SCOPE_AGENT);
        if (old + 1 == GRP*gen){
            __hip_atomic_fetch_add(bar, GRP, __ATOMIC_RELAXED, __HIP_MEMORY_SCOPE_AGENT);
            while (__hip_atomic_load(bar, __ATOMIC_RELAXED, __HIP_MEMORY_SCOPE_AGENT) < NBLK*gen)
                __builtin_amdgcn_s_sleep(2);
            __hip_atomic_fetch_add(gd, 1, __ATOMIC_RELAXED, __HIP_MEMORY_SCOPE_AGENT);
        } else {
            while (__hip_atomic_load(gd, __ATOMIC_RELAXED, __HIP_MEMORY_SCOPE_AGENT) < gen)
                __builtin_amdgcn_s_sleep(2);
        }
        if (inv_gen > 0){
            int x  = get_xcd();
            int nx = __hip_atomic_load(bar + 64*(17+x), __ATOMIC_RELAXED, __HIP_MEMORY_SCOPE_AGENT);
            int* xa = bar + 64*(25+x);
            int* xr = bar + 64*(33+x);
            int o2 = __hip_atomic_fetch_add(xa, 1, __ATOMIC_RELAXED, __HIP_MEMORY_SCOPE_AGENT);
            if (o2 + 1 == nx*inv_gen){
                asm volatile("buffer_inv sc0 sc1\n\ts_waitcnt vmcnt(0)" ::: "memory");
                __hip_atomic_store(xr, inv_gen, __ATOMIC_RELAXED, __HIP_MEMORY_SCOPE_AGENT);
            } else {
                while (__hip_atomic_load(xr, __ATOMIC_RELAXED, __HIP_MEMORY_SCOPE_AGENT) < inv_gen)
                    __builtin_amdgcn_s_sleep(1);
                asm volatile("buffer_inv sc0\n\ts_waitcnt vmcnt(0)" ::: "memory");
            }
        }
    }
    __syncthreads();
}

// ---- K1: dtype probes (bid 0..14 float tensors, 15/16 int tensors) ----
__global__ void probe_all(const void* t0, const void* t1, const void* t2, const void* t3,
                          const void* t4, const void* t5, const void* t6, const void* t7,
                          const void* t8, const void* t9, const void* t10, const void* t11,
                          const void* t12, const void* t13, const void* t14,
                          const int* __restrict__ ids, const int* __restrict__ tree,
                          int* __restrict__ flags){
    const void* ts[15] = {t0,t1,t2,t3,t4,t5,t6,t7,t8,t9,t10,t11,t12,t13,t14};
    int bid = blockIdx.x, t = threadIdx.x;   // 1024 threads
    int bad = 0;
    if (bid < 15){
        if (t < 512){
            unsigned short u = ((const unsigned short*)ts[bid])[t];
            bad = (((u >> 7) & 0xFF) >= 140);
        }
    } else {
        const int* p = (bid == 15) ? ids : tree;
        int n = (bid == 15) ? 1024 : 2048;
        for (int j = t; j < n; j += 1024)
            if (j & 1) bad |= (p[j] != 0);
    }
    unsigned long long bl = __ballot(bad);
    __shared__ int acc[16];
    if ((t & 63) == 0) acc[t >> 6] = (bl != 0ull) ? 1 : 0;
    __syncthreads();
    if (t == 0){
        int any = 0;
        for (int w = 0; w < 16; ++w) any |= acc[w];
        flags[(bid < 15) ? bid : (16 + bid - 15)] = any ? 0 : 1;
    }
}

// ---- K2: rank+CSR-count (bid<8) + all one-time packs + zero-init (512 thr) ----
#define NB2 320
#define GS2 (NB2*512)
__global__ __launch_bounds__(512)
void rank_pack(const void* __restrict__ Wioux, const void* __restrict__ Wfx,
               const void* __restrict__ Wr, const void* __restrict__ Wl,
               const void* __restrict__ W0, const void* __restrict__ W1,
               const void* __restrict__ W2, const void* __restrict__ W3,
               const void* __restrict__ br, const void* __restrict__ bl,
               const void* __restrict__ b0, const void* __restrict__ b1,
               const void* __restrict__ b2, const void* __restrict__ b3,
               const int* __restrict__ ids, const void* __restrict__ emb,
               const int* __restrict__ tree,
               unsigned short* __restrict__ WxT, unsigned short* __restrict__ WcatT,
               float* __restrict__ bcat, unsigned short* __restrict__ xb,
               float* __restrict__ h0,
               int* __restrict__ msk, int* __restrict__ rnk, int* __restrict__ cnt,
               const int* __restrict__ flags, int* __restrict__ bar){
    int bid = blockIdx.x, tid = threadIdx.x;
    int is64 = flags[17];
    if (bid == 0){                         // reset barrier + xcd area (replay-safe)
        for (int i = tid; i < 64*81; i += 512) bar[i] = 0;
    }
    if (bid < 8){
        int st = bid;
        for (int c = tid; c < R_; c += 512){
            cnt[(0*NST + st)*R_ + c] = 0;
            cnt[(1*NST + st)*R_ + c] = 0;
            cnt[(2*NST + st)*R_ + c] = 0;
        }
        __syncthreads();
        __shared__ int wt[8];
        int runbase = 0;
        for (int ch = 0; ch < 2; ++ch){
            int t = ch*512 + tid;
            int b = t >> 7, s = t & 127;
            int base = (b*NST + st)*3*S_;
            int d0 = idx_read(tree, base + s, is64);
            int rd = (b<<7) + d0;
            int rr = (b<<7) + idx_read(tree, base + S_ + s, is64);
            int rl = (b<<7) + idx_read(tree, base + 2*S_ + s, is64);
            int m = (d0 != 0) ? 1 : 0;
            unsigned long long bal = __ballot(m);
            int lane = tid & 63, wv = tid >> 6;
            if (lane == 0) wt[wv] = __popcll(bal);
            __syncthreads();
            int bp = runbase, tot = 0;
            for (int w = 0; w < wv; ++w) bp += wt[w];
            for (int w = 0; w < 8; ++w) tot += wt[w];
            int rank = bp + __popcll(bal & ((1ull << lane) - 1ull));
            msk[st*R_ + t] = m;
            rnk[st*R_ + t] = m ? rank : 0;
            atomicAdd(&cnt[(0*NST + st)*R_ + rr], 1);
            atomicAdd(&cnt[(1*NST + st)*R_ + rl], 1);
            atomicAdd(&cnt[(2*NST + st)*R_ + rd], 1);
            runbase += tot;
            __syncthreads();
        }
    }
    int gt = bid*512 + tid;
    {   // WxT: 2048 n x 64 k-groups
        int f_wx = flags[1], f_wf = flags[6];
        for (int u = gt; u < 131072; u += GS2){
            int n = u >> 6, k0 = (u & 63)*8;
            unsigned short tmp[8];
            #pragma unroll
            for (int i = 0; i < 8; ++i){
                float v = (n < 1536) ? load_in(Wioux, (long long)(k0+i)*1536 + n, f_wx)
                                     : load_in(Wfx,   (long long)(k0+i)*512 + (n-1536), f_wf);
                tmp[i] = f2b(v);
            }
            *(v8s*)&WxT[(size_t)n*KD + k0] = *(v8s*)tmp;
        }
    }
    {   // WcatT
        int fWr=flags[2], fWl=flags[4], fW0=flags[7], fW1=flags[9], fW2=flags[11], fW3=flags[13];
        for (int u = gt; u < 131072; u += GS2){
            int n = u >> 6, k0 = (u & 63)*8;
            unsigned short tmp[8];
            #pragma unroll
            for (int i = 0; i < 8; ++i){
                long long k = k0 + i;
                float v;
                if      (n <  512) v = load_in(Wr, k*1536 + n, fWr);
                else if (n < 1024) v = load_in(Wl, k*1536 + (n-512), fWl);
                else if (n < 1536) { int c = n-1024; v = load_in(W0, k*512+c, fW0) + load_in(W1, k*512+c, fW1); }
                else               { int c = n-1536; v = load_in(W2, k*512+c, fW2) + load_in(W3, k*512+c, fW3); }
                tmp[i] = f2b(v);
            }
            *(v8s*)&WcatT[(size_t)n*KD + k0] = *(v8s*)tmp;
        }
    }
    {   // bcat
        int fbr=flags[3], fbl=flags[5], fb0=flags[8], fb1=flags[10], fb2=flags[12], fb3=flags[14];
        for (int n = gt; n < 2048; n += GS2){
            float v;
            if      (n <  512) v = load_in(br, n, fbr);
            else if (n < 1024) v = load_in(bl, n-512, fbl);
            else if (n < 1536) v = load_in(b0, n-1024, fb0) + load_in(b1, n-1024, fb1);
            else               v = load_in(b2, n-1536, fb2) + load_in(b3, n-1536, fb3);
            bcat[n] = v;
        }
    }
    {   // xb: 1024 rows x 64 groups
        int f_emb = flags[0], i64i = flags[16];
        for (int u = gt; u < 65536; u += GS2){
            int r = u >> 6, c0 = (u & 63)*8;
            long long base = (long long)idx_read(ids, r, i64i)*E_ + c0;
            unsigned short tmp[8];
            #pragma unroll
            for (int i = 0; i < 8; ++i) tmp[i] = f2b(load_in(emb, base + i, f_emb));
            *(v8s*)&xb[(size_t)r*KD + c0] = *(v8s*)tmp;
        }
    }
    for (int u = gt; u < 262144; u += GS2)   // zero h0+c0 (contiguous 4 MB)
        ((float4*)h0)[u] = make_float4(0.f,0.f,0.f,0.f);
}

// ---- K3: CSR scans ----
__global__ void csr_scan(const int* __restrict__ cnt, int* __restrict__ off,
                         int* __restrict__ cur){
    int st = blockIdx.x, a = blockIdx.y;
    int t = threadIdx.x;   // 1024
    int base = (a*NST + st)*R_;
    __shared__ int sh[R_];
    int v = cnt[base + t];
    sh[t] = v;
    __syncthreads();
    for (int d = 1; d < R_; d <<= 1){
        int x = (t >= d) ? sh[t - d] : 0;
        __syncthreads();
        sh[t] += x;
        __syncthreads();
    }
    int excl = sh[t] - v;
    off[base + t] = excl;
    cur[base + t] = excl;
}

// ---- K4: CSR fill ----
__global__ __launch_bounds__(512)
void csr_fill(const int* __restrict__ tree, int* __restrict__ cur,
              int* __restrict__ ent, const int* __restrict__ flags){
    int is64 = flags[17];
    int st = blockIdx.x;
    for (int ch = 0; ch < 2; ++ch){
        int t = ch*512 + threadIdx.x;
        int b = t >> 7, s = t & 127;
        int base = (b*NST + st)*3*S_;
        int rd = (b<<7) + idx_read(tree, base + s, is64);
        int rr = (b<<7) + idx_read(tree, base + S_ + s, is64);
        int rl = (b<<7) + idx_read(tree, base + 2*S_ + s, is64);
        int p0 = atomicAdd(&cur[(0*NST + st)*R_ + rr], 1);
        ent[(0*NST + st)*R_ + p0] = t;
        int p1 = atomicAdd(&cur[(1*NST + st)*R_ + rl], 1);
        ent[(1*NST + st)*R_ + p1] = t;
        int p2 = atomicAdd(&cur[(2*NST + st)*R_ + rd], 1);
        ent[(2*NST + st)*R_ + p2] = t | (rr << 10) | (rl << 20);
    }
}

// ---- GEMM phase (8-wave K-split, full-A-prefetch): C[1024][2048] = A@BT^T ----
// All reads CACHED (L2-coherent via barrier invs); C stored MALL (bypass L2).
__device__ __forceinline__ void gemm_phase(const unsigned short* __restrict__ A,
               const unsigned short* __restrict__ BT,
               const float* __restrict__ bias,
               float* __restrict__ C,
               short* __restrict__ SMEM)
{
    int bid = blockIdx.x;
    int bn = (bid & 7)*4 + ((bid >> 3) & 3);   // bijective on low 5 bits -> 0..31
    int bm = bid >> 5;                          // 0..15
    int tid = threadIdx.x;                      // 0..511
    int lane = tid & 63, wave = tid >> 6;
    int grp = wave >> 2, w4 = wave & 3;
    int wm = w4 & 1, wn = w4 >> 1;
    int lm = lane & 15, quad = lane >> 4;
    short* As = SMEM + grp*(2*64*LDA);
    short* Bs = As + 64*LDA;
    v4f acc[2][2];
    #pragma unroll
    for (int i=0;i<2;++i)
        #pragma unroll
        for (int j=0;j<2;++j) acc[i][j] = (v4f)0.0f;

    int t = tid & 255;
    int srow = t >> 3, sg = (t & 7)*8;
    int kb = grp*256;
    const unsigned short* Ab = A  + (size_t)(bm*64)*KD + kb;
    const unsigned short* Bb = BT + (size_t)(bn*64)*KD + kb;
    v8s pa[4][2], pb[2];
    #pragma unroll
    for (int q=0;q<4;++q)
        #pragma unroll
        for (int j=0;j<2;++j)
            pa[q][j] = *(const v8s*)(Ab + (size_t)(j*32+srow)*KD + q*64 + sg);
    #pragma unroll
    for (int j=0;j<2;++j)
        pb[j] = *(const v8s*)(Bb + (size_t)(j*32+srow)*KD + sg);
    #pragma unroll
    for (int q = 0; q < 4; ++q){
        #pragma unroll
        for (int j=0;j<2;++j){
            *(v8s*)&As[(j*32+srow)*LDA + sg] = pa[q][j];
            *(v8s*)&Bs[(j*32+srow)*LDA + sg] = pb[j];
        }
        __syncthreads();
        if (q < 3){
            #pragma unroll
            for (int j=0;j<2;++j)
                pb[j] = *(const v8s*)(Bb + (size_t)(j*32+srow)*KD + (q+1)*64 + sg);
        }
        #pragma unroll
        for (int kk = 0; kk < 64; kk += 32){
            v8s af[2], bf[2];
            #pragma unroll
            for (int i=0;i<2;++i){
                af[i] = *(const v8s*)&As[(wm*32 + i*16 + lm)*LDA + kk + quad*8];
                bf[i] = *(const v8s*)&Bs[(wn*32 + i*16 + lm)*LDA + kk + quad*8];
            }
            #pragma unroll
            for (int i=0;i<2;++i)
                #pragma unroll
                for (int j=0;j<2;++j)
                    acc[i][j] = __builtin_amdgcn_mfma_f32_16x16x32_bf16(af[i], bf[j], acc[i][j], 0, 0, 0);
        }
        __syncthreads();
    }
    // combine group-1 partials into group-0 accs via LDS (overlays group-0 As/Bs)
    float* Red = (float*)SMEM;
    if (grp){
        #pragma unroll
        for (int i=0;i<2;++i)
            #pragma unroll
            for (int j=0;j<2;++j)
                #pragma unroll
                for (int rg=0;rg<4;++rg)
                    Red[(wm*32 + i*16 + quad*4 + rg)*64 + (wn*32 + j*16 + lm)] = acc[i][j][rg];
    }
    __syncthreads();
    if (!grp){
        #pragma unroll
        for (int j=0;j<2;++j){
            int n = bn*64 + wn*32 + j*16 + lm;
            float bv = bias ? bias[n] : 0.0f;
            #pragma unroll
            for (int i=0;i<2;++i){
                int m0 = bm*64 + wm*32 + i*16 + quad*4;
                #pragma unroll
                for (int rg = 0; rg < 4; ++rg){
                    float v = acc[i][j][rg] + Red[(wm*32 + i*16 + quad*4 + rg)*64 + (wn*32 + j*16 + lm)] + bv;
                    vstore1(&C[(size_t)(m0+rg)*N2 + n], v);
                }
            }
        }
    }
}

// ---- epi phase: CSR-gathered scatters + gates + masked-scatter ----
// 2 rows (r0, r0+1), 1 col/thread. Reads CACHED; state/hb writes MALL.
__device__ __forceinline__ void epi_phase(const float* __restrict__ XO,
              const float* __restrict__ T, int tstr,
              const float* __restrict__ hc, const float* __restrict__ cc,
              float* __restrict__ hn, float* __restrict__ cn,
              unsigned short* __restrict__ hb, float* __restrict__ out,
              const int* __restrict__ msk, const int* __restrict__ rnk,
              const int* __restrict__ cnt, const int* __restrict__ off,
              const int* __restrict__ ent, int st, int last, int r0)
{
    int c = threadIdx.x;     // 0..511
    #pragma unroll
    for (int rr2 = 0; rr2 < 2; ++rr2){
        int r = r0 + rr2;
        if (!msk[st*R_ + r]){
            float hv = hc[(size_t)r*H_ + c];
            if (last){
                out[(size_t)r*H_ + c] = hv;
            } else {
                vstore1(&hn[(size_t)r*H_ + c], hv);
                vstore1(&cn[(size_t)r*H_ + c], cc[(size_t)r*H_ + c]);
                unsigned v16 = f2b(hv);
                unsigned o16 = __shfl_down((int)v16, 1);
                if (!(c & 1)) vstore_hb2(&hb[(size_t)r*KD + c], (unsigned short)v16, (unsigned short)o16);
            }
            continue;
        }
        int j = rnk[st*R_ + r];
        int bR = off[(0*NST+st)*R_ + j], dR = cnt[(0*NST+st)*R_ + j];
        int bL = off[(1*NST+st)*R_ + j], dL = cnt[(1*NST+st)*R_ + j];
        int bD = off[(2*NST+st)*R_ + j], dD = cnt[(2*NST+st)*R_ + j];
        const int* eR = ent + (0*NST+st)*R_ + bR;
        const int* eL = ent + (1*NST+st)*R_ + bL;
        const int* eD = ent + (2*NST+st)*R_ + bD;
        const float* xo = XO + (size_t)j*N2;
        float scv = 0.f;
        {
            int e = 0;
            for (; e + 4 <= dR; e += 4){
                int a0=eR[e], a1=eR[e+1], a2=eR[e+2], a3=eR[e+3];
                float t0 = T[(size_t)a0*tstr + c];
                float t1 = T[(size_t)a1*tstr + c];
                float t2 = T[(size_t)a2*tstr + c];
                float t3 = T[(size_t)a3*tstr + c];
                scv += (t0 + t1) + (t2 + t3);
            }
            for (; e < dR; ++e) scv += T[(size_t)eR[e]*tstr + c];
        }
        {
            int e = 0;
            for (; e + 4 <= dL; e += 4){
                int a0=eL[e], a1=eL[e+1], a2=eL[e+2], a3=eL[e+3];
                float t0 = T[(size_t)a0*tstr + 512 + c];
                float t1 = T[(size_t)a1*tstr + 512 + c];
                float t2 = T[(size_t)a2*tstr + 512 + c];
                float t3 = T[(size_t)a3*tstr + 512 + c];
                scv += (t0 + t1) + (t2 + t3);
            }
            for (; e < dL; ++e) scv += T[(size_t)eL[e]*tstr + 512 + c];
        }
        float fxv = xo[1536 + c];
        float csc = 0.f;
        {
            int e = 0;
            for (; e + 2 <= dD; e += 2){
                int p0 = eD[e], p1 = eD[e+1];
                int s0 = p0 & 1023, ra0 = (p0 >> 10) & 1023, rb0 = (p0 >> 20) & 1023;
                int s1 = p1 & 1023, ra1 = (p1 >> 10) & 1023, rb1 = (p1 >> 20) & 1023;
                float ta0 = T[(size_t)ra0*tstr + 1024 + c];
                float tb0 = T[(size_t)rb0*tstr + 1536 + c];
                float cv0 = cc[(size_t)s0*H_ + c];
                float ta1 = T[(size_t)ra1*tstr + 1024 + c];
                float tb1 = T[(size_t)rb1*tstr + 1536 + c];
                float cv1 = cc[(size_t)s1*H_ + c];
                csc += sigm(fxv + ta0 + tb0) * cv0 + sigm(fxv + ta1 + tb1) * cv1;
            }
            for (; e < dD; ++e){
                int pk = eD[e];
                int s  = pk & 1023, ra = (pk >> 10) & 1023, rb = (pk >> 20) & 1023;
                float ta = T[(size_t)ra*tstr + 1024 + c];
                float tb = T[(size_t)rb*tstr + 1536 + c];
                float cv = cc[(size_t)s*H_ + c];
                csc += sigm(fxv + ta + tb) * cv;
            }
        }
        float ig = sigm(xo[c] + scv);
        float og = sigm(xo[512 + c]);
        float ug = tanhf(xo[1024 + c]);
        float cf = ig*ug + csc;
        float hf = og * tanhf(cf);
        if (last){
            out[(size_t)r*H_ + c] = hf;
        } else {
            vstore1(&hn[(size_t)r*H_ + c], hf);
            vstore1(&cn[(size_t)r*H_ + c], cf);
            unsigned v16 = f2b(hf);
            unsigned o16 = __shfl_down((int)v16, 1);
            if (!(c & 1)) vstore_hb2(&hb[(size_t)r*KD + c], (unsigned short)v16, (unsigned short)o16);
        }
    }
}

// ---- fused chain: r7 barrier skeleton + cached reads + barrier-time invs ----
// Barriers 1-3 need no inv (first cached touch of each buffer); 4+ invalidate
// (hb/T/state rewritten via MALL while stale copies may sit in L2/L1).
__global__ __launch_bounds__(512, 4)
void chain_all(const unsigned short* __restrict__ xb,
               const unsigned short* __restrict__ WxT,
               const unsigned short* __restrict__ WcatT,
               const float* __restrict__ bcat,
               float* __restrict__ XO, float* __restrict__ T,
               float* __restrict__ h0, float* __restrict__ c0,
               float* __restrict__ h1, float* __restrict__ c1,
               unsigned short* __restrict__ hb, float* __restrict__ out,
               const int* __restrict__ msk, const int* __restrict__ rnk,
               const int* __restrict__ cnt, const int* __restrict__ off,
               const int* __restrict__ ent, int* bar)
{
    __shared__ short SMEM[4*64*LDA];   // 2 groups x (As+Bs); also the 16KB Red
    // register this block's XCD (population counts stable after barrier 1)
    if (threadIdx.x == 0){
        int x = get_xcd();
        __hip_atomic_fetch_add(bar + 64*(17+x), 1, __ATOMIC_RELAXED, __HIP_MEMORY_SCOPE_AGENT);
    }
    int r0 = blockIdx.x*2;
    int gen = 0, ig = 0;

    // phase 0: XO = xb @ WxT^T (no bias)
    gemm_phase(xb, WxT, (const float*)nullptr, XO, SMEM);
    gsync(bar, ++gen, 0);
    // step 0: h==0 -> T is the bias broadcast; no GEMM needed (tstr=0, T=bcat)
    epi_phase(XO, bcat, 0, h0, c0, h1, c1, hb, out, msk, rnk, cnt, off, ent, 0, 0, r0);
    gsync(bar, ++gen, 0);

    for (int st = 1; st < NST; ++st){
        const float* hcp = (st & 1) ? h1 : h0;
        const float* ccp = (st & 1) ? c1 : c0;
        float* hnp = (st & 1) ? h0 : h1;
        float* cnp = (st & 1) ? c0 : c1;
        gemm_phase(hb, WcatT, bcat, T, SMEM);
        gsync(bar, ++gen, (st >= 2) ? ++ig : 0);
        epi_phase(XO, T, N2, hcp, ccp, hnp, cnp, hb, out,
                  msk, rnk, cnt, off, ent, st, (st == NST-1) ? 1 : 0, r0);
        if (st < NST-1) gsync(bar, ++gen, ++ig);
    }
}

extern "C" void kernel_launch(void* const* d_in, const int* in_sizes, int n_in,
                              void* d_out, int out_size, void* d_ws, size_t ws_size,
                              hipStream_t stream) {
    const int* input_ids = (const int*)d_in[0];
    const int* tree      = (const int*)d_in[1];

    char* wp = (char*)d_ws;
    auto alloc = [&](size_t bytes) -> void* {
        void* q = (void*)wp;
        wp += (bytes + 255) & ~(size_t)255;
        return q;
    };
    float*          XO     = (float*)alloc((size_t)R_*N2*4);
    float*          T      = (float*)alloc((size_t)R_*N2*4);
    float*          h0     = (float*)alloc((size_t)R_*H_*4);   // contiguous with c0
    float*          c0     = (float*)alloc((size_t)R_*H_*4);
    float*          h1     = (float*)alloc((size_t)R_*H_*4);
    float*          c1     = (float*)alloc((size_t)R_*H_*4);
    unsigned short* WxT    = (unsigned short*)alloc((size_t)N2*KD*2);
    unsigned short* WcatT  = (unsigned short*)alloc((size_t)N2*KD*2);
    float*          bcat   = (float*)alloc((size_t)N2*4);
    unsigned short* xb     = (unsigned short*)alloc((size_t)R_*KD*2);
    unsigned short* hb     = (unsigned short*)alloc((size_t)R_*KD*2);
    int*            msk    = (int*)alloc((size_t)NST*R_*4);
    int*            rnk    = (int*)alloc((size_t)NST*R_*4);
    int*            cnt    = (int*)alloc((size_t)3*NST*R_*4);
    int*            off    = (int*)alloc((size_t)3*NST*R_*4);
    int*            cur    = (int*)alloc((size_t)3*NST*R_*4);
    int*            ent    = (int*)alloc((size_t)3*NST*R_*4);
    int*            flags  = (int*)alloc(256);
    int*            bar    = (int*)alloc(32768);
    float*          out    = (float*)d_out;   // fp32 output (verified r4)

    hipLaunchKernelGGL(probe_all, dim3(17), dim3(1024), 0, stream,
                       d_in[2], d_in[3], d_in[4], d_in[5], d_in[6], d_in[7], d_in[8],
                       d_in[9], d_in[10], d_in[11], d_in[12], d_in[13], d_in[14],
                       d_in[15], d_in[16], input_ids, tree, flags);
    hipLaunchKernelGGL(rank_pack, dim3(NB2), dim3(512), 0, stream,
                       d_in[3], d_in[8],
                       d_in[4], d_in[6], d_in[9], d_in[11], d_in[13], d_in[15],
                       d_in[5], d_in[7], d_in[10], d_in[12], d_in[14], d_in[16],
                       input_ids, d_in[2], tree,
                       WxT, WcatT, bcat, xb, h0, msk, rnk, cnt, flags, bar);
    hipLaunchKernelGGL(csr_scan, dim3(NST, 3), dim3(1024), 0, stream, cnt, off, cur);
    hipLaunchKernelGGL(csr_fill, dim3(NST), dim3(512), 0, stream, tree, cur, ent, flags);

    // single fused kernel for the whole step chain (512 blocks x 512 thr, 2/CU resident)
    hipLaunchKernelGGL(chain_all, dim3(NBLK), dim3(512), 0, stream,
                       xb, WxT, WcatT, bcat, XO, T, h0, c0, h1, c1, hb, out,
                       msk, rnk, cnt, off, ent, bar);
}

// Round 14
// 319.573 us; speedup vs baseline: 1.0303x; 1.0303x over previous
//
#include <hip/hip_runtime.h>
#include <hip/hip_bf16.h>

#define B_ 8
#define S_ 128
#define H_ 512
#define E_ 512
#define NST 8
#define R_ 1024
#define N2 2048
#define KD 512
#define LDA 72          // LDS row pitch in shorts (fragment ds_read_b128: 2-way = free)
#define NBLK 512        // chain grid: 2 blocks/CU x 256 CUs, co-resident by construction
#define GRP 64          // blocks per barrier group (8 groups)

typedef __hip_bfloat16 bf16;
typedef __attribute__((ext_vector_type(8))) short v8s;
typedef __attribute__((ext_vector_type(4))) float v4f;
typedef unsigned long long u64;

__device__ __forceinline__ float sigm(float x){ return 1.0f/(1.0f + expf(-x)); }
__device__ __forceinline__ float load_in(const void* p, long long i, int isb){
    return isb ? __bfloat162float(((const bf16*)p)[i]) : ((const float*)p)[i];
}
__device__ __forceinline__ int idx_read(const int* p, int j, int is64){
    return is64 ? p[2*j] : p[j];
}
__device__ __forceinline__ unsigned short f2b(float v){
    bf16 b = __float2bfloat16(v);
    return *(unsigned short*)&b;
}

// ---- MALL-coherent (agent-scope) access helpers: cross-phase tensors only ----
// (r7-proven data path: relaxed agent atomics bypass non-coherent L1/L2; the
// grid barrier then needs NO cache-maintenance ops.)
__device__ __forceinline__ float vload1f(const float* p){
    return __hip_atomic_load(p, __ATOMIC_RELAXED, __HIP_MEMORY_SCOPE_AGENT);
}
__device__ __forceinline__ float4 vload4f(const float* p){
    union { u64 u[2]; float4 f; } c;
    c.u[0] = __hip_atomic_load((const u64*)p,     __ATOMIC_RELAXED, __HIP_MEMORY_SCOPE_AGENT);
    c.u[1] = __hip_atomic_load(((const u64*)p)+1, __ATOMIC_RELAXED, __HIP_MEMORY_SCOPE_AGENT);
    return c.f;
}
__device__ __forceinline__ void vstore1(float* p, float v){
    __hip_atomic_store(p, v, __ATOMIC_RELAXED, __HIP_MEMORY_SCOPE_AGENT);
}
__device__ __forceinline__ void vstore_hb2(unsigned short* p, unsigned short a, unsigned short b){
    unsigned int u = (unsigned)a | ((unsigned)b << 16);
    __hip_atomic_store((unsigned int*)p, u, __ATOMIC_RELAXED, __HIP_MEMORY_SCOPE_AGENT);
}
__device__ __forceinline__ v8s vload16(const unsigned short* p){
    union { u64 u[2]; v8s v; } c;
    c.u[0] = __hip_atomic_load((const u64*)p,     __ATOMIC_RELAXED, __HIP_MEMORY_SCOPE_AGENT);
    c.u[1] = __hip_atomic_load(((const u64*)p)+1, __ATOMIC_RELAXED, __HIP_MEMORY_SCOPE_AGENT);
    return c.v;
}

// Two-level counter-only grid barrier (proven r4/r7). bar[0..17*64) reserved.
__device__ __forceinline__ void gsync(int* bar, int gen){
    __syncthreads();
    if (threadIdx.x == 0){
        int g = blockIdx.x >> 6;
        int* ga = bar + 64*(1+g);
        int* gd = bar + 64*(9+g);
        int old = __hip_atomic_fetch_add(ga, 1, __ATOMIC_RELAXED, __HIP_MEMORY_SCOPE_AGENT);
        if (old + 1 == GRP*gen){
            __hip_atomic_fetch_add(bar, GRP, __ATOMIC_RELAXED, __HIP_MEMORY_SCOPE_AGENT);
            while (__hip_atomic_load(bar, __ATOMIC_RELAXED, __HIP_MEMORY_SCOPE_AGENT) < NBLK*gen)
                __builtin_amdgcn_s_sleep(2);
            __hip_atomic_fetch_add(gd, 1, __ATOMIC_RELAXED, __HIP_MEMORY_SCOPE_AGENT);
        } else {
            while (__hip_atomic_load(gd, __ATOMIC_RELAXED, __HIP_MEMORY_SCOPE_AGENT) < gen)
                __builtin_amdgcn_s_sleep(2);
        }
    }
    __syncthreads();
}

// ---- K1: dtype probes (bid 0..14 float tensors, 15/16 int tensors) ----
__global__ void probe_all(const void* t0, const void* t1, const void* t2, const void* t3,
                          const void* t4, const void* t5, const void* t6, const void* t7,
                          const void* t8, const void* t9, const void* t10, const void* t11,
                          const void* t12, const void* t13, const void* t14,
                          const int* __restrict__ ids, const int* __restrict__ tree,
                          int* __restrict__ flags){
    const void* ts[15] = {t0,t1,t2,t3,t4,t5,t6,t7,t8,t9,t10,t11,t12,t13,t14};
    int bid = blockIdx.x, t = threadIdx.x;   // 1024 threads
    int bad = 0;
    if (bid < 15){
        if (t < 512){
            unsigned short u = ((const unsigned short*)ts[bid])[t];
            bad = (((u >> 7) & 0xFF) >= 140);
        }
    } else {
        const int* p = (bid == 15) ? ids : tree;
        int n = (bid == 15) ? 1024 : 2048;
        for (int j = t; j < n; j += 1024)
            if (j & 1) bad |= (p[j] != 0);
    }
    unsigned long long bl = __ballot(bad);
    __shared__ int acc[16];
    if ((t & 63) == 0) acc[t >> 6] = (bl != 0ull) ? 1 : 0;
    __syncthreads();
    if (t == 0){
        int any = 0;
        for (int w = 0; w < 16; ++w) any |= acc[w];
        flags[(bid < 15) ? bid : (16 + bid - 15)] = any ? 0 : 1;
    }
}

// ---- K2: rank+CSR-count (bid<8) + all one-time packs + zero-init (512 thr) ----
#define NB2 320
#define GS2 (NB2*512)
__global__ __launch_bounds__(512)
void rank_pack(const void* __restrict__ Wioux, const void* __restrict__ Wfx,
               const void* __restrict__ Wr, const void* __restrict__ Wl,
               const void* __restrict__ W0, const void* __restrict__ W1,
               const void* __restrict__ W2, const void* __restrict__ W3,
               const void* __restrict__ br, const void* __restrict__ bl,
               const void* __restrict__ b0, const void* __restrict__ b1,
               const void* __restrict__ b2, const void* __restrict__ b3,
               const int* __restrict__ ids, const void* __restrict__ emb,
               const int* __restrict__ tree,
               unsigned short* __restrict__ WxT, unsigned short* __restrict__ WcatT,
               float* __restrict__ bcat, unsigned short* __restrict__ xb,
               float* __restrict__ h0,
               int* __restrict__ msk, int* __restrict__ rnk, int* __restrict__ cnt,
               const int* __restrict__ flags, int* __restrict__ bar){
    int bid = blockIdx.x, tid = threadIdx.x;
    int is64 = flags[17];
    if (bid == 0){                         // reset chain barrier block (replay-safe)
        for (int i = tid; i < 64*17; i += 512) bar[i] = 0;
    }
    if (bid < 8){
        int st = bid;
        for (int c = tid; c < R_; c += 512){
            cnt[(0*NST + st)*R_ + c] = 0;
            cnt[(1*NST + st)*R_ + c] = 0;
            cnt[(2*NST + st)*R_ + c] = 0;
        }
        __syncthreads();
        __shared__ int wt[8];
        int runbase = 0;
        for (int ch = 0; ch < 2; ++ch){
            int t = ch*512 + tid;
            int b = t >> 7, s = t & 127;
            int base = (b*NST + st)*3*S_;
            int d0 = idx_read(tree, base + s, is64);
            int rd = (b<<7) + d0;
            int rr = (b<<7) + idx_read(tree, base + S_ + s, is64);
            int rl = (b<<7) + idx_read(tree, base + 2*S_ + s, is64);
            int m = (d0 != 0) ? 1 : 0;
            unsigned long long bal = __ballot(m);
            int lane = tid & 63, wv = tid >> 6;
            if (lane == 0) wt[wv] = __popcll(bal);
            __syncthreads();
            int bp = runbase, tot = 0;
            for (int w = 0; w < wv; ++w) bp += wt[w];
            for (int w = 0; w < 8; ++w) tot += wt[w];
            int rank = bp + __popcll(bal & ((1ull << lane) - 1ull));
            msk[st*R_ + t] = m;
            rnk[st*R_ + t] = m ? rank : 0;
            atomicAdd(&cnt[(0*NST + st)*R_ + rr], 1);
            atomicAdd(&cnt[(1*NST + st)*R_ + rl], 1);
            atomicAdd(&cnt[(2*NST + st)*R_ + rd], 1);
            runbase += tot;
            __syncthreads();
        }
    }
    int gt = bid*512 + tid;
    {   // WxT: 2048 n x 64 k-groups
        int f_wx = flags[1], f_wf = flags[6];
        for (int u = gt; u < 131072; u += GS2){
            int n = u >> 6, k0 = (u & 63)*8;
            unsigned short tmp[8];
            #pragma unroll
            for (int i = 0; i < 8; ++i){
                float v = (n < 1536) ? load_in(Wioux, (long long)(k0+i)*1536 + n, f_wx)
                                     : load_in(Wfx,   (long long)(k0+i)*512 + (n-1536), f_wf);
                tmp[i] = f2b(v);
            }
            *(v8s*)&WxT[(size_t)n*KD + k0] = *(v8s*)tmp;
        }
    }
    {   // WcatT
        int fWr=flags[2], fWl=flags[4], fW0=flags[7], fW1=flags[9], fW2=flags[11], fW3=flags[13];
        for (int u = gt; u < 131072; u += GS2){
            int n = u >> 6, k0 = (u & 63)*8;
            unsigned short tmp[8];
            #pragma unroll
            for (int i = 0; i < 8; ++i){
                long long k = k0 + i;
                float v;
                if      (n <  512) v = load_in(Wr, k*1536 + n, fWr);
                else if (n < 1024) v = load_in(Wl, k*1536 + (n-512), fWl);
                else if (n < 1536) { int c = n-1024; v = load_in(W0, k*512+c, fW0) + load_in(W1, k*512+c, fW1); }
                else               { int c = n-1536; v = load_in(W2, k*512+c, fW2) + load_in(W3, k*512+c, fW3); }
                tmp[i] = f2b(v);
            }
            *(v8s*)&WcatT[(size_t)n*KD + k0] = *(v8s*)tmp;
        }
    }
    {   // bcat
        int fbr=flags[3], fbl=flags[5], fb0=flags[8], fb1=flags[10], fb2=flags[12], fb3=flags[14];
        for (int n = gt; n < 2048; n += GS2){
            float v;
            if      (n <  512) v = load_in(br, n, fbr);
            else if (n < 1024) v = load_in(bl, n-512, fbl);
            else if (n < 1536) v = load_in(b0, n-1024, fb0) + load_in(b1, n-1024, fb1);
            else               v = load_in(b2, n-1536, fb2) + load_in(b3, n-1536, fb3);
            bcat[n] = v;
        }
    }
    {   // xb: 1024 rows x 64 groups
        int f_emb = flags[0], i64i = flags[16];
        for (int u = gt; u < 65536; u += GS2){
            int r = u >> 6, c0 = (u & 63)*8;
            long long base = (long long)idx_read(ids, r, i64i)*E_ + c0;
            unsigned short tmp[8];
            #pragma unroll
            for (int i = 0; i < 8; ++i) tmp[i] = f2b(load_in(emb, base + i, f_emb));
            *(v8s*)&xb[(size_t)r*KD + c0] = *(v8s*)tmp;
        }
    }
    for (int u = gt; u < 262144; u += GS2)   // zero h0+c0 (contiguous 4 MB)
        ((float4*)h0)[u] = make_float4(0.f,0.f,0.f,0.f);
}

// ---- K3: CSR scans ----
__global__ void csr_scan(const int* __restrict__ cnt, int* __restrict__ off,
                         int* __restrict__ cur){
    int st = blockIdx.x, a = blockIdx.y;
    int t = threadIdx.x;   // 1024
    int base = (a*NST + st)*R_;
    __shared__ int sh[R_];
    int v = cnt[base + t];
    sh[t] = v;
    __syncthreads();
    for (int d = 1; d < R_; d <<= 1){
        int x = (t >= d) ? sh[t - d] : 0;
        __syncthreads();
        sh[t] += x;
        __syncthreads();
    }
    int excl = sh[t] - v;
    off[base + t] = excl;
    cur[base + t] = excl;
}

// ---- K4: CSR fill (widened: 64 blocks x 128 thr; list order is irrelevant) ----
__global__ __launch_bounds__(128)
void csr_fill(const int* __restrict__ tree, int* __restrict__ cur,
              int* __restrict__ ent, const int* __restrict__ flags){
    int is64 = flags[17];
    int st = blockIdx.x >> 3;
    int t  = ((blockIdx.x & 7) << 7) + threadIdx.x;   // 0..1023
    int b = t >> 7, s = t & 127;
    int base = (b*NST + st)*3*S_;
    int rd = (b<<7) + idx_read(tree, base + s, is64);
    int rr = (b<<7) + idx_read(tree, base + S_ + s, is64);
    int rl = (b<<7) + idx_read(tree, base + 2*S_ + s, is64);
    int p0 = atomicAdd(&cur[(0*NST + st)*R_ + rr], 1);
    ent[(0*NST + st)*R_ + p0] = t;
    int p1 = atomicAdd(&cur[(1*NST + st)*R_ + rl], 1);
    ent[(1*NST + st)*R_ + p1] = t;
    int p2 = atomicAdd(&cur[(2*NST + st)*R_ + rd], 1);
    ent[(2*NST + st)*R_ + p2] = t | (rr << 10) | (rl << 20);
}

// ---- GEMM phase (8-wave K-split, full-A-prefetch): C[1024][2048] = A@BT^T ----
// A (hb/xb) via MALL loads (1 prefetch round for all 4 K-chunks); B cached.
// pack=1: write C in [m][512][4] float4-slice layout (XO only).
__device__ __forceinline__ void gemm_phase(const unsigned short* __restrict__ A,
               const unsigned short* __restrict__ BT,
               const float* __restrict__ bias,
               float* __restrict__ C, int pack,
               short* __restrict__ SMEM)
{
    int bid = blockIdx.x;
    int bn = (bid & 7)*4 + ((bid >> 3) & 3);   // bijective on low 5 bits -> 0..31
    int bm = bid >> 5;                          // 0..15
    int tid = threadIdx.x;                      // 0..511
    int lane = tid & 63, wave = tid >> 6;
    int grp = wave >> 2, w4 = wave & 3;
    int wm = w4 & 1, wn = w4 >> 1;
    int lm = lane & 15, quad = lane >> 4;
    short* As = SMEM + grp*(2*64*LDA);
    short* Bs = As + 64*LDA;
    v4f acc[2][2];
    #pragma unroll
    for (int i=0;i<2;++i)
        #pragma unroll
        for (int j=0;j<2;++j) acc[i][j] = (v4f)0.0f;

    int t = tid & 255;
    int srow = t >> 3, sg = (t & 7)*8;
    int kb = grp*256;
    const unsigned short* Ab = A  + (size_t)(bm*64)*KD + kb;
    const unsigned short* Bb = BT + (size_t)(bn*64)*KD + kb;
    v8s pa[4][2], pb[2];
    #pragma unroll
    for (int q=0;q<4;++q)
        #pragma unroll
        for (int j=0;j<2;++j)
            pa[q][j] = vload16(Ab + (size_t)(j*32+srow)*KD + q*64 + sg);
    #pragma unroll
    for (int j=0;j<2;++j)
        pb[j] = *(const v8s*)(Bb + (size_t)(j*32+srow)*KD + sg);
    #pragma unroll
    for (int q = 0; q < 4; ++q){
        #pragma unroll
        for (int j=0;j<2;++j){
            *(v8s*)&As[(j*32+srow)*LDA + sg] = pa[q][j];
            *(v8s*)&Bs[(j*32+srow)*LDA + sg] = pb[j];
        }
        __syncthreads();
        if (q < 3){
            #pragma unroll
            for (int j=0;j<2;++j)
                pb[j] = *(const v8s*)(Bb + (size_t)(j*32+srow)*KD + (q+1)*64 + sg);
        }
        #pragma unroll
        for (int kk = 0; kk < 64; kk += 32){
            v8s af[2], bf[2];
            #pragma unroll
            for (int i=0;i<2;++i){
                af[i] = *(const v8s*)&As[(wm*32 + i*16 + lm)*LDA + kk + quad*8];
                bf[i] = *(const v8s*)&Bs[(wn*32 + i*16 + lm)*LDA + kk + quad*8];
            }
            #pragma unroll
            for (int i=0;i<2;++i)
                #pragma unroll
                for (int j=0;j<2;++j)
                    acc[i][j] = __builtin_amdgcn_mfma_f32_16x16x32_bf16(af[i], bf[j], acc[i][j], 0, 0, 0);
        }
        __syncthreads();
    }
    // combine group-1 partials into group-0 accs via LDS (overlays group-0 As/Bs)
    float* Red = (float*)SMEM;
    if (grp){
        #pragma unroll
        for (int i=0;i<2;++i)
            #pragma unroll
            for (int j=0;j<2;++j)
                #pragma unroll
                for (int rg=0;rg<4;++rg)
                    Red[(wm*32 + i*16 + quad*4 + rg)*64 + (wn*32 + j*16 + lm)] = acc[i][j][rg];
    }
    __syncthreads();
    if (!grp){
        #pragma unroll
        for (int j=0;j<2;++j){
            int n = bn*64 + wn*32 + j*16 + lm;
            float bv = bias ? bias[n] : 0.0f;
            int noff = pack ? (((n & 511) << 2) + (n >> 9)) : n;
            #pragma unroll
            for (int i=0;i<2;++i){
                int m0 = bm*64 + wm*32 + i*16 + quad*4;
                #pragma unroll
                for (int rg = 0; rg < 4; ++rg){
                    float v = acc[i][j][rg] + Red[(wm*32 + i*16 + quad*4 + rg)*64 + (wn*32 + j*16 + lm)] + bv;
                    vstore1(&C[(size_t)(m0+rg)*N2 + noff], v);
                }
            }
        }
    }
}

// ---- epi phase: CSR-gathered scatters + gates + masked-scatter ----
// 2 rows (r0, r0+1), 1 col/thread. Deep-batched MALL loads: R/L x8, D x4
// (12 loads in flight) to cut serial latency rounds for high-fan-in rows.
// XO is float4-packed: one 16B load for [i,o,u,fx].
__device__ __forceinline__ void epi_phase(const float* __restrict__ XO,
              const float* __restrict__ T, int tstr,
              const float* __restrict__ hc, const float* __restrict__ cc,
              float* __restrict__ hn, float* __restrict__ cn,
              unsigned short* __restrict__ hb, float* __restrict__ out,
              const int* __restrict__ msk, const int* __restrict__ rnk,
              const int* __restrict__ cnt, const int* __restrict__ off,
              const int* __restrict__ ent, int st, int last, int r0)
{
    int c = threadIdx.x;     // 0..511
    #pragma unroll
    for (int rr2 = 0; rr2 < 2; ++rr2){
        int r = r0 + rr2;
        if (!msk[st*R_ + r]){
            float hv = vload1f(&hc[(size_t)r*H_ + c]);
            if (last){
                out[(size_t)r*H_ + c] = hv;
            } else {
                vstore1(&hn[(size_t)r*H_ + c], hv);
                vstore1(&cn[(size_t)r*H_ + c], vload1f(&cc[(size_t)r*H_ + c]));
                unsigned v16 = f2b(hv);
                unsigned o16 = __shfl_down((int)v16, 1);
                if (!(c & 1)) vstore_hb2(&hb[(size_t)r*KD + c], (unsigned short)v16, (unsigned short)o16);
            }
            continue;
        }
        int j = rnk[st*R_ + r];
        int bR = off[(0*NST+st)*R_ + j], dR = cnt[(0*NST+st)*R_ + j];
        int bL = off[(1*NST+st)*R_ + j], dL = cnt[(1*NST+st)*R_ + j];
        int bD = off[(2*NST+st)*R_ + j], dD = cnt[(2*NST+st)*R_ + j];
        const int* eR = ent + (0*NST+st)*R_ + bR;
        const int* eL = ent + (1*NST+st)*R_ + bL;
        const int* eD = ent + (2*NST+st)*R_ + bD;
        float4 x4 = vload4f(XO + (size_t)j*N2 + (size_t)c*4);   // [i,o,u,fx]
        float scv = 0.f;
        {
            int e = 0;
            for (; e + 8 <= dR; e += 8){
                float t0 = vload1f(&T[(size_t)eR[e  ]*tstr + c]);
                float t1 = vload1f(&T[(size_t)eR[e+1]*tstr + c]);
                float t2 = vload1f(&T[(size_t)eR[e+2]*tstr + c]);
                float t3 = vload1f(&T[(size_t)eR[e+3]*tstr + c]);
                float t4 = vload1f(&T[(size_t)eR[e+4]*tstr + c]);
                float t5 = vload1f(&T[(size_t)eR[e+5]*tstr + c]);
                float t6 = vload1f(&T[(size_t)eR[e+6]*tstr + c]);
                float t7 = vload1f(&T[(size_t)eR[e+7]*tstr + c]);
                scv += ((t0 + t1) + (t2 + t3)) + ((t4 + t5) + (t6 + t7));
            }
            for (; e + 4 <= dR; e += 4){
                float t0 = vload1f(&T[(size_t)eR[e  ]*tstr + c]);
                float t1 = vload1f(&T[(size_t)eR[e+1]*tstr + c]);
                float t2 = vload1f(&T[(size_t)eR[e+2]*tstr + c]);
                float t3 = vload1f(&T[(size_t)eR[e+3]*tstr + c]);
                scv += (t0 + t1) + (t2 + t3);
            }
            for (; e < dR; ++e) scv += vload1f(&T[(size_t)eR[e]*tstr + c]);
        }
        {
            int e = 0;
            for (; e + 8 <= dL; e += 8){
                float t0 = vload1f(&T[(size_t)eL[e  ]*tstr + 512 + c]);
                float t1 = vload1f(&T[(size_t)eL[e+1]*tstr + 512 + c]);
                float t2 = vload1f(&T[(size_t)eL[e+2]*tstr + 512 + c]);
                float t3 = vload1f(&T[(size_t)eL[e+3]*tstr + 512 + c]);
                float t4 = vload1f(&T[(size_t)eL[e+4]*tstr + 512 + c]);
                float t5 = vload1f(&T[(size_t)eL[e+5]*tstr + 512 + c]);
                float t6 = vload1f(&T[(size_t)eL[e+6]*tstr + 512 + c]);
                float t7 = vload1f(&T[(size_t)eL[e+7]*tstr + 512 + c]);
                scv += ((t0 + t1) + (t2 + t3)) + ((t4 + t5) + (t6 + t7));
            }
            for (; e + 4 <= dL; e += 4){
                float t0 = vload1f(&T[(size_t)eL[e  ]*tstr + 512 + c]);
                float t1 = vload1f(&T[(size_t)eL[e+1]*tstr + 512 + c]);
                float t2 = vload1f(&T[(size_t)eL[e+2]*tstr + 512 + c]);
                float t3 = vload1f(&T[(size_t)eL[e+3]*tstr + 512 + c]);
                scv += (t0 + t1) + (t2 + t3);
            }
            for (; e < dL; ++e) scv += vload1f(&T[(size_t)eL[e]*tstr + 512 + c]);
        }
        float fxv = x4.w;
        float csc = 0.f;
        {
            int e = 0;
            for (; e + 4 <= dD; e += 4){
                int p0 = eD[e], p1 = eD[e+1], p2 = eD[e+2], p3 = eD[e+3];
                int s0 = p0 & 1023, ra0 = (p0 >> 10) & 1023, rb0 = (p0 >> 20) & 1023;
                int s1 = p1 & 1023, ra1 = (p1 >> 10) & 1023, rb1 = (p1 >> 20) & 1023;
                int s2 = p2 & 1023, ra2 = (p2 >> 10) & 1023, rb2 = (p2 >> 20) & 1023;
                int s3 = p3 & 1023, ra3 = (p3 >> 10) & 1023, rb3 = (p3 >> 20) & 1023;
                float ta0 = vload1f(&T[(size_t)ra0*tstr + 1024 + c]);
                float tb0 = vload1f(&T[(size_t)rb0*tstr + 1536 + c]);
                float cv0 = vload1f(&cc[(size_t)s0*H_ + c]);
                float ta1 = vload1f(&T[(size_t)ra1*tstr + 1024 + c]);
                float tb1 = vload1f(&T[(size_t)rb1*tstr + 1536 + c]);
                float cv1 = vload1f(&cc[(size_t)s1*H_ + c]);
                float ta2 = vload1f(&T[(size_t)ra2*tstr + 1024 + c]);
                float tb2 = vload1f(&T[(size_t)rb2*tstr + 1536 + c]);
                float cv2 = vload1f(&cc[(size_t)s2*H_ + c]);
                float ta3 = vload1f(&T[(size_t)ra3*tstr + 1024 + c]);
                float tb3 = vload1f(&T[(size_t)rb3*tstr + 1536 + c]);
                float cv3 = vload1f(&cc[(size_t)s3*H_ + c]);
                csc += (sigm(fxv + ta0 + tb0) * cv0 + sigm(fxv + ta1 + tb1) * cv1)
                     + (sigm(fxv + ta2 + tb2) * cv2 + sigm(fxv + ta3 + tb3) * cv3);
            }
            for (; e < dD; ++e){
                int pk = eD[e];
                int s  = pk & 1023, ra = (pk >> 10) & 1023, rb = (pk >> 20) & 1023;
                float ta = vload1f(&T[(size_t)ra*tstr + 1024 + c]);
                float tb = vload1f(&T[(size_t)rb*tstr + 1536 + c]);
                float cv = vload1f(&cc[(size_t)s*H_ + c]);
                csc += sigm(fxv + ta + tb) * cv;
            }
        }
        float ig = sigm(x4.x + scv);
        float og = sigm(x4.y);
        float ug = tanhf(x4.z);
        float cf = ig*ug + csc;
        float hf = og * tanhf(cf);
        if (last){
            out[(size_t)r*H_ + c] = hf;
        } else {
            vstore1(&hn[(size_t)r*H_ + c], hf);
            vstore1(&cn[(size_t)r*H_ + c], cf);
            unsigned v16 = f2b(hf);
            unsigned o16 = __shfl_down((int)v16, 1);
            if (!(c & 1)) vstore_hb2(&hb[(size_t)r*KD + c], (unsigned short)v16, (unsigned short)o16);
        }
    }
}

// ---- fused chain: r7 barrier skeleton (proven best) + deep-batched epi ----
__global__ __launch_bounds__(512, 4)
void chain_all(const unsigned short* __restrict__ xb,
               const unsigned short* __restrict__ WxT,
               const unsigned short* __restrict__ WcatT,
               const float* __restrict__ bcat,
               float* __restrict__ XO, float* __restrict__ T,
               float* __restrict__ h0, float* __restrict__ c0,
               float* __restrict__ h1, float* __restrict__ c1,
               unsigned short* __restrict__ hb, float* __restrict__ out,
               const int* __restrict__ msk, const int* __restrict__ rnk,
               const int* __restrict__ cnt, const int* __restrict__ off,
               const int* __restrict__ ent, int* bar)
{
    __shared__ short SMEM[4*64*LDA];   // 2 groups x (As+Bs); also the 16KB Red
    int r0 = blockIdx.x*2;
    int gen = 0;

    // phase 0: XO = xb @ WxT^T (no bias), float4-slice packed layout
    gemm_phase(xb, WxT, (const float*)nullptr, XO, 1, SMEM);
    gsync(bar, ++gen);
    // step 0: h==0 -> T is the bias broadcast; no GEMM needed (tstr=0, T=bcat)
    epi_phase(XO, bcat, 0, h0, c0, h1, c1, hb, out, msk, rnk, cnt, off, ent, 0, 0, r0);
    gsync(bar, ++gen);

    for (int st = 1; st < NST; ++st){
        const float* hcp = (st & 1) ? h1 : h0;
        const float* ccp = (st & 1) ? c1 : c0;
        float* hnp = (st & 1) ? h0 : h1;
        float* cnp = (st & 1) ? c0 : c1;
        gemm_phase(hb, WcatT, bcat, T, 0, SMEM);
        gsync(bar, ++gen);
        epi_phase(XO, T, N2, hcp, ccp, hnp, cnp, hb, out,
                  msk, rnk, cnt, off, ent, st, (st == NST-1) ? 1 : 0, r0);
        if (st < NST-1) gsync(bar, ++gen);
    }
}

extern "C" void kernel_launch(void* const* d_in, const int* in_sizes, int n_in,
                              void* d_out, int out_size, void* d_ws, size_t ws_size,
                              hipStream_t stream) {
    const int* input_ids = (const int*)d_in[0];
    const int* tree      = (const int*)d_in[1];

    char* wp = (char*)d_ws;
    auto alloc = [&](size_t bytes) -> void* {
        void* q = (void*)wp;
        wp += (bytes + 255) & ~(size_t)255;
        return q;
    };
    float*          XO     = (float*)alloc((size_t)R_*N2*4);
    float*          T      = (float*)alloc((size_t)R_*N2*4);
    float*          h0     = (float*)alloc((size_t)R_*H_*4);   // contiguous with c0
    float*          c0     = (float*)alloc((size_t)R_*H_*4);
    float*          h1     = (float*)alloc((size_t)R_*H_*4);
    float*          c1     = (float*)alloc((size_t)R_*H_*4);
    unsigned short* WxT    = (unsigned short*)alloc((size_t)N2*KD*2);
    unsigned short* WcatT  = (unsigned short*)alloc((size_t)N2*KD*2);
    float*          bcat   = (float*)alloc((size_t)N2*4);
    unsigned short* xb     = (unsigned short*)alloc((size_t)R_*KD*2);
    unsigned short* hb     = (unsigned short*)alloc((size_t)R_*KD*2);
    int*            msk    = (int*)alloc((size_t)NST*R_*4);
    int*            rnk    = (int*)alloc((size_t)NST*R_*4);
    int*            cnt    = (int*)alloc((size_t)3*NST*R_*4);
    int*            off    = (int*)alloc((size_t)3*NST*R_*4);
    int*            cur    = (int*)alloc((size_t)3*NST*R_*4);
    int*            ent    = (int*)alloc((size_t)3*NST*R_*4);
    int*            flags  = (int*)alloc(256);
    int*            bar    = (int*)alloc(8192);
    float*          out    = (float*)d_out;   // fp32 output (verified r4)

    hipLaunchKernelGGL(probe_all, dim3(17), dim3(1024), 0, stream,
                       d_in[2], d_in[3], d_in[4], d_in[5], d_in[6], d_in[7], d_in[8],
                       d_in[9], d_in[10], d_in[11], d_in[12], d_in[13], d_in[14],
                       d_in[15], d_in[16], input_ids, tree, flags);
    hipLaunchKernelGGL(rank_pack, dim3(NB2), dim3(512), 0, stream,
                       d_in[3], d_in[8],
                       d_in[4], d_in[6], d_in[9], d_in[11], d_in[13], d_in[15],
                       d_in[5], d_in[7], d_in[10], d_in[12], d_in[14], d_in[16],
                       input_ids, d_in[2], tree,
                       WxT, WcatT, bcat, xb, h0, msk, rnk, cnt, flags, bar);
    hipLaunchKernelGGL(csr_scan, dim3(NST, 3), dim3(1024), 0, stream, cnt, off, cur);
    hipLaunchKernelGGL(csr_fill, dim3(NST*8), dim3(128), 0, stream, tree, cur, ent, flags);

    // single fused kernel for the whole step chain (512 blocks x 512 thr, 2/CU resident)
    hipLaunchKernelGGL(chain_all, dim3(NBLK), dim3(512), 0, stream,
                       xb, WxT, WcatT, bcat, XO, T, h0, c0, h1, c1, hb, out,
                       msk, rnk, cnt, off, ent, bar);
}

// Round 15
// 317.615 us; speedup vs baseline: 1.0367x; 1.0062x over previous
//
#include <hip/hip_runtime.h>
#include <hip/hip_bf16.h>

#define B_ 8
#define S_ 128
#define H_ 512
#define E_ 512
#define NST 8
#define R_ 1024
#define N2 2048
#define KD 512
#define LDA 72          // LDS row pitch in shorts (fragment ds_read_b128: 2-way = free)
#define NBLK 512        // chain grid: 2 blocks/CU x 256 CUs, co-resident by construction
#define GRP 64          // blocks per barrier group (8 groups)

typedef __hip_bfloat16 bf16;
typedef __attribute__((ext_vector_type(8))) short v8s;
typedef __attribute__((ext_vector_type(4))) float v4f;
typedef unsigned long long u64;

__device__ __forceinline__ float sigm(float x){ return 1.0f/(1.0f + expf(-x)); }
__device__ __forceinline__ float load_in(const void* p, long long i, int isb){
    return isb ? __bfloat162float(((const bf16*)p)[i]) : ((const float*)p)[i];
}
__device__ __forceinline__ int idx_read(const int* p, int j, int is64){
    return is64 ? p[2*j] : p[j];
}
__device__ __forceinline__ unsigned short f2b(float v){
    bf16 b = __float2bfloat16(v);
    return *(unsigned short*)&b;
}

// ---- MALL-coherent (agent-scope) access helpers: cross-phase tensors only ----
// (r7-proven data path: relaxed agent atomics bypass non-coherent L1/L2; the
// grid barrier then needs NO cache-maintenance ops.)
__device__ __forceinline__ float vload1f(const float* p){
    return __hip_atomic_load(p, __ATOMIC_RELAXED, __HIP_MEMORY_SCOPE_AGENT);
}
__device__ __forceinline__ void vstore1(float* p, float v){
    __hip_atomic_store(p, v, __ATOMIC_RELAXED, __HIP_MEMORY_SCOPE_AGENT);
}
__device__ __forceinline__ void vstore_hb2(unsigned short* p, unsigned short a, unsigned short b){
    unsigned int u = (unsigned)a | ((unsigned)b << 16);
    __hip_atomic_store((unsigned int*)p, u, __ATOMIC_RELAXED, __HIP_MEMORY_SCOPE_AGENT);
}
__device__ __forceinline__ v8s vload16(const unsigned short* p){
    union { u64 u[2]; v8s v; } c;
    c.u[0] = __hip_atomic_load((const u64*)p,     __ATOMIC_RELAXED, __HIP_MEMORY_SCOPE_AGENT);
    c.u[1] = __hip_atomic_load(((const u64*)p)+1, __ATOMIC_RELAXED, __HIP_MEMORY_SCOPE_AGENT);
    return c.v;
}

// Two-level counter-only grid barrier (proven r4/r7). bar[0..17*64) reserved.
__device__ __forceinline__ void gsync(int* bar, int gen){
    __syncthreads();
    if (threadIdx.x == 0){
        int g = blockIdx.x >> 6;
        int* ga = bar + 64*(1+g);
        int* gd = bar + 64*(9+g);
        int old = __hip_atomic_fetch_add(ga, 1, __ATOMIC_RELAXED, __HIP_MEMORY_SCOPE_AGENT);
        if (old + 1 == GRP*gen){
            __hip_atomic_fetch_add(bar, GRP, __ATOMIC_RELAXED, __HIP_MEMORY_SCOPE_AGENT);
            while (__hip_atomic_load(bar, __ATOMIC_RELAXED, __HIP_MEMORY_SCOPE_AGENT) < NBLK*gen)
                __builtin_amdgcn_s_sleep(2);
            __hip_atomic_fetch_add(gd, 1, __ATOMIC_RELAXED, __HIP_MEMORY_SCOPE_AGENT);
        } else {
            while (__hip_atomic_load(gd, __ATOMIC_RELAXED, __HIP_MEMORY_SCOPE_AGENT) < gen)
                __builtin_amdgcn_s_sleep(2);
        }
    }
    __syncthreads();
}

// ---- K1: dtype probes (bid 0..14 float tensors, 15/16 int tensors) ----
__global__ void probe_all(const void* t0, const void* t1, const void* t2, const void* t3,
                          const void* t4, const void* t5, const void* t6, const void* t7,
                          const void* t8, const void* t9, const void* t10, const void* t11,
                          const void* t12, const void* t13, const void* t14,
                          const int* __restrict__ ids, const int* __restrict__ tree,
                          int* __restrict__ flags){
    const void* ts[15] = {t0,t1,t2,t3,t4,t5,t6,t7,t8,t9,t10,t11,t12,t13,t14};
    int bid = blockIdx.x, t = threadIdx.x;   // 1024 threads
    int bad = 0;
    if (bid < 15){
        if (t < 512){
            unsigned short u = ((const unsigned short*)ts[bid])[t];
            bad = (((u >> 7) & 0xFF) >= 140);
        }
    } else {
        const int* p = (bid == 15) ? ids : tree;
        int n = (bid == 15) ? 1024 : 2048;
        for (int j = t; j < n; j += 1024)
            if (j & 1) bad |= (p[j] != 0);
    }
    unsigned long long bl = __ballot(bad);
    __shared__ int acc[16];
    if ((t & 63) == 0) acc[t >> 6] = (bl != 0ull) ? 1 : 0;
    __syncthreads();
    if (t == 0){
        int any = 0;
        for (int w = 0; w < 16; ++w) any |= acc[w];
        flags[(bid < 15) ? bid : (16 + bid - 15)] = any ? 0 : 1;
    }
}

// ---- K2: rank+CSR-count (bid<8) + all one-time packs + zero-init (512 thr) ----
#define NB2 320
#define GS2 (NB2*512)
__global__ __launch_bounds__(512)
void rank_pack(const void* __restrict__ Wioux, const void* __restrict__ Wfx,
               const void* __restrict__ Wr, const void* __restrict__ Wl,
               const void* __restrict__ W0, const void* __restrict__ W1,
               const void* __restrict__ W2, const void* __restrict__ W3,
               const void* __restrict__ br, const void* __restrict__ bl,
               const void* __restrict__ b0, const void* __restrict__ b1,
               const void* __restrict__ b2, const void* __restrict__ b3,
               const int* __restrict__ ids, const void* __restrict__ emb,
               const int* __restrict__ tree,
               unsigned short* __restrict__ WxT, unsigned short* __restrict__ WcatT,
               float* __restrict__ bcat, unsigned short* __restrict__ xb,
               float* __restrict__ h0,
               int* __restrict__ msk, int* __restrict__ rnk, int* __restrict__ cnt,
               const int* __restrict__ flags, int* __restrict__ bar){
    int bid = blockIdx.x, tid = threadIdx.x;
    int is64 = flags[17];
    if (bid == 0){                         // reset chain barrier block (replay-safe)
        for (int i = tid; i < 64*17; i += 512) bar[i] = 0;
    }
    if (bid < 8){
        int st = bid;
        for (int c = tid; c < R_; c += 512){
            cnt[(0*NST + st)*R_ + c] = 0;
            cnt[(1*NST + st)*R_ + c] = 0;
            cnt[(2*NST + st)*R_ + c] = 0;
        }
        __syncthreads();
        __shared__ int wt[8];
        int runbase = 0;
        for (int ch = 0; ch < 2; ++ch){
            int t = ch*512 + tid;
            int b = t >> 7, s = t & 127;
            int base = (b*NST + st)*3*S_;
            int d0 = idx_read(tree, base + s, is64);
            int rd = (b<<7) + d0;
            int rr = (b<<7) + idx_read(tree, base + S_ + s, is64);
            int rl = (b<<7) + idx_read(tree, base + 2*S_ + s, is64);
            int m = (d0 != 0) ? 1 : 0;
            unsigned long long bal = __ballot(m);
            int lane = tid & 63, wv = tid >> 6;
            if (lane == 0) wt[wv] = __popcll(bal);
            __syncthreads();
            int bp = runbase, tot = 0;
            for (int w = 0; w < wv; ++w) bp += wt[w];
            for (int w = 0; w < 8; ++w) tot += wt[w];
            int rank = bp + __popcll(bal & ((1ull << lane) - 1ull));
            msk[st*R_ + t] = m;
            rnk[st*R_ + t] = m ? rank : 0;
            atomicAdd(&cnt[(0*NST + st)*R_ + rr], 1);
            atomicAdd(&cnt[(1*NST + st)*R_ + rl], 1);
            atomicAdd(&cnt[(2*NST + st)*R_ + rd], 1);
            runbase += tot;
            __syncthreads();
        }
    }
    int gt = bid*512 + tid;
    {   // WxT: 2048 n x 64 k-groups
        int f_wx = flags[1], f_wf = flags[6];
        for (int u = gt; u < 131072; u += GS2){
            int n = u >> 6, k0 = (u & 63)*8;
            unsigned short tmp[8];
            #pragma unroll
            for (int i = 0; i < 8; ++i){
                float v = (n < 1536) ? load_in(Wioux, (long long)(k0+i)*1536 + n, f_wx)
                                     : load_in(Wfx,   (long long)(k0+i)*512 + (n-1536), f_wf);
                tmp[i] = f2b(v);
            }
            *(v8s*)&WxT[(size_t)n*KD + k0] = *(v8s*)tmp;
        }
    }
    {   // WcatT
        int fWr=flags[2], fWl=flags[4], fW0=flags[7], fW1=flags[9], fW2=flags[11], fW3=flags[13];
        for (int u = gt; u < 131072; u += GS2){
            int n = u >> 6, k0 = (u & 63)*8;
            unsigned short tmp[8];
            #pragma unroll
            for (int i = 0; i < 8; ++i){
                long long k = k0 + i;
                float v;
                if      (n <  512) v = load_in(Wr, k*1536 + n, fWr);
                else if (n < 1024) v = load_in(Wl, k*1536 + (n-512), fWl);
                else if (n < 1536) { int c = n-1024; v = load_in(W0, k*512+c, fW0) + load_in(W1, k*512+c, fW1); }
                else               { int c = n-1536; v = load_in(W2, k*512+c, fW2) + load_in(W3, k*512+c, fW3); }
                tmp[i] = f2b(v);
            }
            *(v8s*)&WcatT[(size_t)n*KD + k0] = *(v8s*)tmp;
        }
    }
    {   // bcat
        int fbr=flags[3], fbl=flags[5], fb0=flags[8], fb1=flags[10], fb2=flags[12], fb3=flags[14];
        for (int n = gt; n < 2048; n += GS2){
            float v;
            if      (n <  512) v = load_in(br, n, fbr);
            else if (n < 1024) v = load_in(bl, n-512, fbl);
            else if (n < 1536) v = load_in(b0, n-1024, fb0) + load_in(b1, n-1024, fb1);
            else               v = load_in(b2, n-1536, fb2) + load_in(b3, n-1536, fb3);
            bcat[n] = v;
        }
    }
    {   // xb: 1024 rows x 64 groups
        int f_emb = flags[0], i64i = flags[16];
        for (int u = gt; u < 65536; u += GS2){
            int r = u >> 6, c0 = (u & 63)*8;
            long long base = (long long)idx_read(ids, r, i64i)*E_ + c0;
            unsigned short tmp[8];
            #pragma unroll
            for (int i = 0; i < 8; ++i) tmp[i] = f2b(load_in(emb, base + i, f_emb));
            *(v8s*)&xb[(size_t)r*KD + c0] = *(v8s*)tmp;
        }
    }
    for (int u = gt; u < 262144; u += GS2)   // zero h0+c0 (contiguous 4 MB)
        ((float4*)h0)[u] = make_float4(0.f,0.f,0.f,0.f);
}

// ---- K3: CSR scans ----
__global__ void csr_scan(const int* __restrict__ cnt, int* __restrict__ off,
                         int* __restrict__ cur){
    int st = blockIdx.x, a = blockIdx.y;
    int t = threadIdx.x;   // 1024
    int base = (a*NST + st)*R_;
    __shared__ int sh[R_];
    int v = cnt[base + t];
    sh[t] = v;
    __syncthreads();
    for (int d = 1; d < R_; d <<= 1){
        int x = (t >= d) ? sh[t - d] : 0;
        __syncthreads();
        sh[t] += x;
        __syncthreads();
    }
    int excl = sh[t] - v;
    off[base + t] = excl;
    cur[base + t] = excl;
}

// ---- K4: CSR fill (widened: 64 blocks x 128 thr; list order is irrelevant) ----
__global__ __launch_bounds__(128)
void csr_fill(const int* __restrict__ tree, int* __restrict__ cur,
              int* __restrict__ ent, const int* __restrict__ flags){
    int is64 = flags[17];
    int st = blockIdx.x >> 3;
    int t  = ((blockIdx.x & 7) << 7) + threadIdx.x;   // 0..1023
    int b = t >> 7, s = t & 127;
    int base = (b*NST + st)*3*S_;
    int rd = (b<<7) + idx_read(tree, base + s, is64);
    int rr = (b<<7) + idx_read(tree, base + S_ + s, is64);
    int rl = (b<<7) + idx_read(tree, base + 2*S_ + s, is64);
    int p0 = atomicAdd(&cur[(0*NST + st)*R_ + rr], 1);
    ent[(0*NST + st)*R_ + p0] = t;
    int p1 = atomicAdd(&cur[(1*NST + st)*R_ + rl], 1);
    ent[(1*NST + st)*R_ + p1] = t;
    int p2 = atomicAdd(&cur[(2*NST + st)*R_ + rd], 1);
    ent[(2*NST + st)*R_ + p2] = t | (rr << 10) | (rl << 20);
}

// ---- GEMM phase (8-wave K-split, full-A-prefetch): C[1024][2048] = A@BT^T ----
// A (hb/xb) via MALL loads (1 prefetch round for all 4 K-chunks); B cached.
// C written in NORMAL coalesced layout (r14's packed layout caused 4x write
// amplification at HBM: WRITE +40MB, FETCH +66MB -> reverted).
__device__ __forceinline__ void gemm_phase(const unsigned short* __restrict__ A,
               const unsigned short* __restrict__ BT,
               const float* __restrict__ bias,
               float* __restrict__ C,
               short* __restrict__ SMEM)
{
    int bid = blockIdx.x;
    int bn = (bid & 7)*4 + ((bid >> 3) & 3);   // bijective on low 5 bits -> 0..31
    int bm = bid >> 5;                          // 0..15
    int tid = threadIdx.x;                      // 0..511
    int lane = tid & 63, wave = tid >> 6;
    int grp = wave >> 2, w4 = wave & 3;
    int wm = w4 & 1, wn = w4 >> 1;
    int lm = lane & 15, quad = lane >> 4;
    short* As = SMEM + grp*(2*64*LDA);
    short* Bs = As + 64*LDA;
    v4f acc[2][2];
    #pragma unroll
    for (int i=0;i<2;++i)
        #pragma unroll
        for (int j=0;j<2;++j) acc[i][j] = (v4f)0.0f;

    int t = tid & 255;
    int srow = t >> 3, sg = (t & 7)*8;
    int kb = grp*256;
    const unsigned short* Ab = A  + (size_t)(bm*64)*KD + kb;
    const unsigned short* Bb = BT + (size_t)(bn*64)*KD + kb;
    v8s pa[4][2], pb[2];
    #pragma unroll
    for (int q=0;q<4;++q)
        #pragma unroll
        for (int j=0;j<2;++j)
            pa[q][j] = vload16(Ab + (size_t)(j*32+srow)*KD + q*64 + sg);
    #pragma unroll
    for (int j=0;j<2;++j)
        pb[j] = *(const v8s*)(Bb + (size_t)(j*32+srow)*KD + sg);
    #pragma unroll
    for (int q = 0; q < 4; ++q){
        #pragma unroll
        for (int j=0;j<2;++j){
            *(v8s*)&As[(j*32+srow)*LDA + sg] = pa[q][j];
            *(v8s*)&Bs[(j*32+srow)*LDA + sg] = pb[j];
        }
        __syncthreads();
        if (q < 3){
            #pragma unroll
            for (int j=0;j<2;++j)
                pb[j] = *(const v8s*)(Bb + (size_t)(j*32+srow)*KD + (q+1)*64 + sg);
        }
        #pragma unroll
        for (int kk = 0; kk < 64; kk += 32){
            v8s af[2], bf[2];
            #pragma unroll
            for (int i=0;i<2;++i){
                af[i] = *(const v8s*)&As[(wm*32 + i*16 + lm)*LDA + kk + quad*8];
                bf[i] = *(const v8s*)&Bs[(wn*32 + i*16 + lm)*LDA + kk + quad*8];
            }
            #pragma unroll
            for (int i=0;i<2;++i)
                #pragma unroll
                for (int j=0;j<2;++j)
                    acc[i][j] = __builtin_amdgcn_mfma_f32_16x16x32_bf16(af[i], bf[j], acc[i][j], 0, 0, 0);
        }
        __syncthreads();
    }
    // combine group-1 partials into group-0 accs via LDS (overlays group-0 As/Bs)
    float* Red = (float*)SMEM;
    if (grp){
        #pragma unroll
        for (int i=0;i<2;++i)
            #pragma unroll
            for (int j=0;j<2;++j)
                #pragma unroll
                for (int rg=0;rg<4;++rg)
                    Red[(wm*32 + i*16 + quad*4 + rg)*64 + (wn*32 + j*16 + lm)] = acc[i][j][rg];
    }
    __syncthreads();
    if (!grp){
        #pragma unroll
        for (int j=0;j<2;++j){
            int n = bn*64 + wn*32 + j*16 + lm;
            float bv = bias ? bias[n] : 0.0f;
            #pragma unroll
            for (int i=0;i<2;++i){
                int m0 = bm*64 + wm*32 + i*16 + quad*4;
                #pragma unroll
                for (int rg = 0; rg < 4; ++rg){
                    float v = acc[i][j][rg] + Red[(wm*32 + i*16 + quad*4 + rg)*64 + (wn*32 + j*16 + lm)] + bv;
                    vstore1(&C[(size_t)(m0+rg)*N2 + n], v);
                }
            }
        }
    }
}

// ---- epi phase: CSR-gathered scatters + gates + masked-scatter ----
// 2 rows (r0, r0+1), 1 col/thread. Deep-batched MALL loads: R/L x8, D x4
// (12 loads in flight) to cut serial latency rounds for high-fan-in rows.
// 4 gate loads issued up-front so they overlap the first T batch.
__device__ __forceinline__ void epi_phase(const float* __restrict__ XO,
              const float* __restrict__ T, int tstr,
              const float* __restrict__ hc, const float* __restrict__ cc,
              float* __restrict__ hn, float* __restrict__ cn,
              unsigned short* __restrict__ hb, float* __restrict__ out,
              const int* __restrict__ msk, const int* __restrict__ rnk,
              const int* __restrict__ cnt, const int* __restrict__ off,
              const int* __restrict__ ent, int st, int last, int r0)
{
    int c = threadIdx.x;     // 0..511
    #pragma unroll
    for (int rr2 = 0; rr2 < 2; ++rr2){
        int r = r0 + rr2;
        if (!msk[st*R_ + r]){
            float hv = vload1f(&hc[(size_t)r*H_ + c]);
            if (last){
                out[(size_t)r*H_ + c] = hv;
            } else {
                vstore1(&hn[(size_t)r*H_ + c], hv);
                vstore1(&cn[(size_t)r*H_ + c], vload1f(&cc[(size_t)r*H_ + c]));
                unsigned v16 = f2b(hv);
                unsigned o16 = __shfl_down((int)v16, 1);
                if (!(c & 1)) vstore_hb2(&hb[(size_t)r*KD + c], (unsigned short)v16, (unsigned short)o16);
            }
            continue;
        }
        int j = rnk[st*R_ + r];
        int bR = off[(0*NST+st)*R_ + j], dR = cnt[(0*NST+st)*R_ + j];
        int bL = off[(1*NST+st)*R_ + j], dL = cnt[(1*NST+st)*R_ + j];
        int bD = off[(2*NST+st)*R_ + j], dD = cnt[(2*NST+st)*R_ + j];
        const int* eR = ent + (0*NST+st)*R_ + bR;
        const int* eL = ent + (1*NST+st)*R_ + bL;
        const int* eD = ent + (2*NST+st)*R_ + bD;
        const float* xo = XO + (size_t)j*N2;
        // issue all 4 gate loads up-front (overlap with first T batch)
        float xi  = vload1f(&xo[c]);
        float xq  = vload1f(&xo[512 + c]);
        float xu  = vload1f(&xo[1024 + c]);
        float fxv = vload1f(&xo[1536 + c]);
        float scv = 0.f;
        {
            int e = 0;
            for (; e + 8 <= dR; e += 8){
                float t0 = vload1f(&T[(size_t)eR[e  ]*tstr + c]);
                float t1 = vload1f(&T[(size_t)eR[e+1]*tstr + c]);
                float t2 = vload1f(&T[(size_t)eR[e+2]*tstr + c]);
                float t3 = vload1f(&T[(size_t)eR[e+3]*tstr + c]);
                float t4 = vload1f(&T[(size_t)eR[e+4]*tstr + c]);
                float t5 = vload1f(&T[(size_t)eR[e+5]*tstr + c]);
                float t6 = vload1f(&T[(size_t)eR[e+6]*tstr + c]);
                float t7 = vload1f(&T[(size_t)eR[e+7]*tstr + c]);
                scv += ((t0 + t1) + (t2 + t3)) + ((t4 + t5) + (t6 + t7));
            }
            for (; e + 4 <= dR; e += 4){
                float t0 = vload1f(&T[(size_t)eR[e  ]*tstr + c]);
                float t1 = vload1f(&T[(size_t)eR[e+1]*tstr + c]);
                float t2 = vload1f(&T[(size_t)eR[e+2]*tstr + c]);
                float t3 = vload1f(&T[(size_t)eR[e+3]*tstr + c]);
                scv += (t0 + t1) + (t2 + t3);
            }
            for (; e < dR; ++e) scv += vload1f(&T[(size_t)eR[e]*tstr + c]);
        }
        {
            int e = 0;
            for (; e + 8 <= dL; e += 8){
                float t0 = vload1f(&T[(size_t)eL[e  ]*tstr + 512 + c]);
                float t1 = vload1f(&T[(size_t)eL[e+1]*tstr + 512 + c]);
                float t2 = vload1f(&T[(size_t)eL[e+2]*tstr + 512 + c]);
                float t3 = vload1f(&T[(size_t)eL[e+3]*tstr + 512 + c]);
                float t4 = vload1f(&T[(size_t)eL[e+4]*tstr + 512 + c]);
                float t5 = vload1f(&T[(size_t)eL[e+5]*tstr + 512 + c]);
                float t6 = vload1f(&T[(size_t)eL[e+6]*tstr + 512 + c]);
                float t7 = vload1f(&T[(size_t)eL[e+7]*tstr + 512 + c]);
                scv += ((t0 + t1) + (t2 + t3)) + ((t4 + t5) + (t6 + t7));
            }
            for (; e + 4 <= dL; e += 4){
                float t0 = vload1f(&T[(size_t)eL[e  ]*tstr + 512 + c]);
                float t1 = vload1f(&T[(size_t)eL[e+1]*tstr + 512 + c]);
                float t2 = vload1f(&T[(size_t)eL[e+2]*tstr + 512 + c]);
                float t3 = vload1f(&T[(size_t)eL[e+3]*tstr + 512 + c]);
                scv += (t0 + t1) + (t2 + t3);
            }
            for (; e < dL; ++e) scv += vload1f(&T[(size_t)eL[e]*tstr + 512 + c]);
        }
        float csc = 0.f;
        {
            int e = 0;
            for (; e + 4 <= dD; e += 4){
                int p0 = eD[e], p1 = eD[e+1], p2 = eD[e+2], p3 = eD[e+3];
                int s0 = p0 & 1023, ra0 = (p0 >> 10) & 1023, rb0 = (p0 >> 20) & 1023;
                int s1 = p1 & 1023, ra1 = (p1 >> 10) & 1023, rb1 = (p1 >> 20) & 1023;
                int s2 = p2 & 1023, ra2 = (p2 >> 10) & 1023, rb2 = (p2 >> 20) & 1023;
                int s3 = p3 & 1023, ra3 = (p3 >> 10) & 1023, rb3 = (p3 >> 20) & 1023;
                float ta0 = vload1f(&T[(size_t)ra0*tstr + 1024 + c]);
                float tb0 = vload1f(&T[(size_t)rb0*tstr + 1536 + c]);
                float cv0 = vload1f(&cc[(size_t)s0*H_ + c]);
                float ta1 = vload1f(&T[(size_t)ra1*tstr + 1024 + c]);
                float tb1 = vload1f(&T[(size_t)rb1*tstr + 1536 + c]);
                float cv1 = vload1f(&cc[(size_t)s1*H_ + c]);
                float ta2 = vload1f(&T[(size_t)ra2*tstr + 1024 + c]);
                float tb2 = vload1f(&T[(size_t)rb2*tstr + 1536 + c]);
                float cv2 = vload1f(&cc[(size_t)s2*H_ + c]);
                float ta3 = vload1f(&T[(size_t)ra3*tstr + 1024 + c]);
                float tb3 = vload1f(&T[(size_t)rb3*tstr + 1536 + c]);
                float cv3 = vload1f(&cc[(size_t)s3*H_ + c]);
                csc += (sigm(fxv + ta0 + tb0) * cv0 + sigm(fxv + ta1 + tb1) * cv1)
                     + (sigm(fxv + ta2 + tb2) * cv2 + sigm(fxv + ta3 + tb3) * cv3);
            }
            for (; e < dD; ++e){
                int pk = eD[e];
                int s  = pk & 1023, ra = (pk >> 10) & 1023, rb = (pk >> 20) & 1023;
                float ta = vload1f(&T[(size_t)ra*tstr + 1024 + c]);
                float tb = vload1f(&T[(size_t)rb*tstr + 1536 + c]);
                float cv = vload1f(&cc[(size_t)s*H_ + c]);
                csc += sigm(fxv + ta + tb) * cv;
            }
        }
        float ig = sigm(xi + scv);
        float og = sigm(xq);
        float ug = tanhf(xu);
        float cf = ig*ug + csc;
        float hf = og * tanhf(cf);
        if (last){
            out[(size_t)r*H_ + c] = hf;
        } else {
            vstore1(&hn[(size_t)r*H_ + c], hf);
            vstore1(&cn[(size_t)r*H_ + c], cf);
            unsigned v16 = f2b(hf);
            unsigned o16 = __shfl_down((int)v16, 1);
            if (!(c & 1)) vstore_hb2(&hb[(size_t)r*KD + c], (unsigned short)v16, (unsigned short)o16);
        }
    }
}

// ---- fused chain: r7 barrier skeleton (proven best) + deep-batched epi ----
__global__ __launch_bounds__(512, 4)
void chain_all(const unsigned short* __restrict__ xb,
               const unsigned short* __restrict__ WxT,
               const unsigned short* __restrict__ WcatT,
               const float* __restrict__ bcat,
               float* __restrict__ XO, float* __restrict__ T,
               float* __restrict__ h0, float* __restrict__ c0,
               float* __restrict__ h1, float* __restrict__ c1,
               unsigned short* __restrict__ hb, float* __restrict__ out,
               const int* __restrict__ msk, const int* __restrict__ rnk,
               const int* __restrict__ cnt, const int* __restrict__ off,
               const int* __restrict__ ent, int* bar)
{
    __shared__ short SMEM[4*64*LDA];   // 2 groups x (As+Bs); also the 16KB Red
    int r0 = blockIdx.x*2;
    int gen = 0;

    // phase 0: XO = xb @ WxT^T (no bias), normal coalesced layout
    gemm_phase(xb, WxT, (const float*)nullptr, XO, SMEM);
    gsync(bar, ++gen);
    // step 0: h==0 -> T is the bias broadcast; no GEMM needed (tstr=0, T=bcat)
    epi_phase(XO, bcat, 0, h0, c0, h1, c1, hb, out, msk, rnk, cnt, off, ent, 0, 0, r0);
    gsync(bar, ++gen);

    for (int st = 1; st < NST; ++st){
        const float* hcp = (st & 1) ? h1 : h0;
        const float* ccp = (st & 1) ? c1 : c0;
        float* hnp = (st & 1) ? h0 : h1;
        float* cnp = (st & 1) ? c0 : c1;
        gemm_phase(hb, WcatT, bcat, T, SMEM);
        gsync(bar, ++gen);
        epi_phase(XO, T, N2, hcp, ccp, hnp, cnp, hb, out,
                  msk, rnk, cnt, off, ent, st, (st == NST-1) ? 1 : 0, r0);
        if (st < NST-1) gsync(bar, ++gen);
    }
}

extern "C" void kernel_launch(void* const* d_in, const int* in_sizes, int n_in,
                              void* d_out, int out_size, void* d_ws, size_t ws_size,
                              hipStream_t stream) {
    const int* input_ids = (const int*)d_in[0];
    const int* tree      = (const int*)d_in[1];

    char* wp = (char*)d_ws;
    auto alloc = [&](size_t bytes) -> void* {
        void* q = (void*)wp;
        wp += (bytes + 255) & ~(size_t)255;
        return q;
    };
    float*          XO     = (float*)alloc((size_t)R_*N2*4);
    float*          T      = (float*)alloc((size_t)R_*N2*4);
    float*          h0     = (float*)alloc((size_t)R_*H_*4);   // contiguous with c0
    float*          c0     = (float*)alloc((size_t)R_*H_*4);
    float*          h1     = (float*)alloc((size_t)R_*H_*4);
    float*          c1     = (float*)alloc((size_t)R_*H_*4);
    unsigned short* WxT    = (unsigned short*)alloc((size_t)N2*KD*2);
    unsigned short* WcatT  = (unsigned short*)alloc((size_t)N2*KD*2);
    float*          bcat   = (float*)alloc((size_t)N2*4);
    unsigned short* xb     = (unsigned short*)alloc((size_t)R_*KD*2);
    unsigned short* hb     = (unsigned short*)alloc((size_t)R_*KD*2);
    int*            msk    = (int*)alloc((size_t)NST*R_*4);
    int*            rnk    = (int*)alloc((size_t)NST*R_*4);
    int*            cnt    = (int*)alloc((size_t)3*NST*R_*4);
    int*            off    = (int*)alloc((size_t)3*NST*R_*4);
    int*            cur    = (int*)alloc((size_t)3*NST*R_*4);
    int*            ent    = (int*)alloc((size_t)3*NST*R_*4);
    int*            flags  = (int*)alloc(256);
    int*            bar    = (int*)alloc(8192);
    float*          out    = (float*)d_out;   // fp32 output (verified r4)

    hipLaunchKernelGGL(probe_all, dim3(17), dim3(1024), 0, stream,
                       d_in[2], d_in[3], d_in[4], d_in[5], d_in[6], d_in[7], d_in[8],
                       d_in[9], d_in[10], d_in[11], d_in[12], d_in[13], d_in[14],
                       d_in[15], d_in[16], input_ids, tree, flags);
    hipLaunchKernelGGL(rank_pack, dim3(NB2), dim3(512), 0, stream,
                       d_in[3], d_in[8],
                       d_in[4], d_in[6], d_in[9], d_in[11], d_in[13], d_in[15],
                       d_in[5], d_in[7], d_in[10], d_in[12], d_in[14], d_in[16],
                       input_ids, d_in[2], tree,
                       WxT, WcatT, bcat, xb, h0, msk, rnk, cnt, flags, bar);
    hipLaunchKernelGGL(csr_scan, dim3(NST, 3), dim3(1024), 0, stream, cnt, off, cur);
    hipLaunchKernelGGL(csr_fill, dim3(NST*8), dim3(128), 0, stream, tree, cur, ent, flags);

    // single fused kernel for the whole step chain (512 blocks x 512 thr, 2/CU resident)
    hipLaunchKernelGGL(chain_all, dim3(NBLK), dim3(512), 0, stream,
                       xb, WxT, WcatT, bcat, XO, T, h0, c0, h1, c1, hb, out,
                       msk, rnk, cnt, off, ent, bar);
}